// Round 5
// baseline (99.235 us; speedup 1.0000x reference)
//
#include <hip/hip_runtime.h>

#define B_ 32
#define C_ 64          // Cin = Cout
#define H_ 112
#define W_ 112
#define HW (H_ * W_)
#define HG_ 14               // h-groups per image (8 rows each)
#define TILES_ 4             // 2-row tiles per block
#define NBLKC (B_ * HG_)     // 448 conv blocks, %8==0 for XCD swizzle

#define SLOTS 114            // slot = w+1; slots 0,113 are zeros
#define CHUNK 128            // bytes per (h,slot): 64 cin bf16
#define XROWB (SLOTS * CHUNK)              // 14592 B per (b,h)
#define XROWCH (XROWB / 16)                // 912 16B-chunks per row
#define XT_BYTES ((size_t)B_ * H_ * XROWB) // ~52.3 MB
#define WQ_OFF 131072

typedef short bf16x8 __attribute__((ext_vector_type(8)));
typedef float f32x4 __attribute__((ext_vector_type(4)));
typedef unsigned int u32;

#define GLOAD_LDS(g, l, sz)                                                   \
    __builtin_amdgcn_global_load_lds(                                         \
        (const __attribute__((address_space(1))) u32*)(const void*)(g),       \
        (__attribute__((address_space(3))) u32*)(void*)(l), (sz), 0, 0)

__device__ inline unsigned short f2bf(float f) {
    union { float f; unsigned u; } v;
    v.f = f;
    unsigned u = v.u;
    u += 0x7fffu + ((u >> 16) & 1u);   // RNE
    return (unsigned short)(u >> 16);
}

// w[co][cin][kh][kw] fp32 -> wq[shift][co][cin] bf16 sign
__global__ void quant_w(const float* __restrict__ w,
                        unsigned short* __restrict__ wq) {
    int i = blockIdx.x * 256 + threadIdx.x;
    if (i >= C_ * C_ * 9) return;
    int k   = i % 9;
    int cin = (i / 9) % C_;
    int co  = i / (9 * C_);
    float v = w[i];
    float q = (v > 0.f) ? 1.f : ((v < 0.f) ? -1.f : 0.f);
    wq[(k * C_ + co) * C_ + cin] = f2bf(q);
}

// ---------------------------------------------------------------------------
// Transform: x[b][c][h][w] fp32 -> xt[b][h][slot][cin] bf16, pre-swizzled:
// dword for cin-pair cp lives at byte (cp*4)^((slot&7)<<4) within the chunk.
// (measured round 4: runs at HBM floor ~25 us)
// ---------------------------------------------------------------------------
__global__ __launch_bounds__(256) void xform(const float* __restrict__ x,
                                             unsigned short* __restrict__ xt) {
    __shared__ unsigned short pl[C_ * SLOTS];

    const int tid = threadIdx.x;
    const int b   = blockIdx.x / H_;
    const int h   = blockIdx.x % H_;

#pragma unroll
    for (int it = 0; it < 7; ++it) {
        const int u  = tid + 256 * it;        // < 1792 = 64c * 28 quads
        const int c  = u / 28;
        const int w4 = u % 28;
        const f32x4 v =
            *(const f32x4*)(x + ((size_t)(b * C_ + c) * H_ + h) * W_ + w4 * 4);
        const u32 lo = (u32)f2bf(v[0]) | ((u32)f2bf(v[1]) << 16);
        const u32 hi = (u32)f2bf(v[2]) | ((u32)f2bf(v[3]) << 16);
        u32* p = (u32*)&pl[c * SLOTS + w4 * 4];
        p[0] = lo;
        p[1] = hi;
    }
    __syncthreads();

    unsigned short* xtrow = xt + (size_t)(b * H_ + h) * (XROWB / 2);
#pragma unroll
    for (int it = 0; it < 15; ++it) {
        const int u = tid + 256 * it;         // < 3648 = 114 * 32
        if (u < SLOTS * 32) {
            const int slot = u >> 5;
            const int cp   = u & 31;
            u32 val = 0;
            if (1 <= slot && slot <= 112) {
                const int w = slot - 1;
                val = (u32)pl[(2 * cp) * SLOTS + w] |
                      ((u32)pl[(2 * cp + 1) * SLOTS + w] << 16);
            }
            *(u32*)((char*)xtrow + slot * CHUNK +
                    ((cp * 4) ^ ((slot & 7) << 4))) = val;
        }
    }
}

// ---------------------------------------------------------------------------
// Persistent ring-pipelined conv. Block = (b, hgroup of 8 output rows) =
// 4 tiles of 2 rows. LDS = ring of 4 row-slots; slot(xrow) = (xrow+1)&3.
// Per tile: {issue reg-prefetch of 2 next rows} -> {252 MFMA/wave} ->
// {stores} -> barrier -> {ds_write prefetch} -> barrier.
// ---------------------------------------------------------------------------
__global__ __launch_bounds__(256) void conv_mfma(
    const unsigned short* __restrict__ xt, const unsigned short* __restrict__ wq,
    const float* __restrict__ bias, const float* __restrict__ scale,
    float* __restrict__ out) {
    __shared__ char xs[4 * XROWB];   // 58368 B -> 2 blocks/CU

    const int tid  = threadIdx.x;
    const int lane = tid & 63;
    const int wave = tid >> 6;
    const int lcol = lane & 15;
    const int kg   = lane >> 4;
    const int mw   = wave >> 1;      // cout half
    const int nw   = wave & 1;       // row within tile

    const int bid = blockIdx.x;
    const int s   = (bid & 7) * (NBLKC / 8) + (bid >> 3);   // XCD-bijective
    const int b   = s / HG_;
    const int hg  = s % HG_;
    const int h0base = hg * 8;

    const char* xtc = (const char*)xt + (size_t)b * H_ * XROWB;

    // ---- prologue: stage rows h0base-1 .. h0base+2 into ring slots ----
    {
        const int r    = wave;
        const int xrow = h0base - 1 + r;
        char* dst = xs + ((h0base + r) & 3) * XROWB;
        if (0 <= xrow && xrow < H_) {
            const char* src = xtc + (size_t)xrow * XROWB + lane * 16;
#pragma unroll
            for (int ch = 0; ch < 14; ++ch)
                GLOAD_LDS(src + ch * 1024, dst + ch * 1024, 16);
            GLOAD_LDS(xtc + (size_t)xrow * XROWB + 14336 + lane * 4,
                      dst + 14336, 4);
        } else {
            char* d = dst + lane * 16;
            const f32x4 z = {0.f, 0.f, 0.f, 0.f};
#pragma unroll
            for (int ch = 0; ch < 14; ++ch) *(f32x4*)(d + ch * 1024) = z;
            *(u32*)(dst + 14336 + lane * 4) = 0u;
        }
    }
    __syncthreads();

    // swizzle-adjusted K-offsets (same addressing round 4 verified)
    int koff[3][2];
#pragma unroll
    for (int dw = 0; dw < 3; ++dw) {
        const int key = ((lcol + dw) & 7) << 4;
        koff[dw][0] = (kg * 16) ^ key;
        koff[dw][1] = (64 + kg * 16) ^ key;
    }

    const unsigned short* wqa = wq + (mw * 32 + lcol) * C_ + kg * 8;
    const float sc = scale[0];
    f32x4 bs[2];
#pragma unroll
    for (int m = 0; m < 2; ++m)
        bs[m] = *(const f32x4*)(bias + mw * 32 + m * 16 + kg * 4);

    for (int t = 0; t < TILES_; ++t) {
        const int h0 = h0base + 2 * t;
        const bool havepf = (t < TILES_ - 1);

        // ---- issue reg-prefetch of rows h0+3, h0+4 (oldest in vmcnt q) ----
        f32x4 pf[7];
        f32x4 pf8;
#pragma unroll
        for (int i = 0; i < 7; ++i) {
            const int q   = tid + 256 * i;          // < 1792 of 1824 chunks
            const int row = (q >= XROWCH) ? 1 : 0;
            const int off = (q - row * XROWCH) * 16;
            const int xrow = h0 + 3 + row;
            f32x4 v = {0.f, 0.f, 0.f, 0.f};
            if (havepf && xrow < H_)
                v = *(const f32x4*)(xtc + (size_t)xrow * XROWB + off);
            pf[i] = v;
        }
        {
            const int q   = 1792 + tid;             // tail 32 chunks (row 1)
            const int off = (q - XROWCH) * 16;
            const int xrow = h0 + 4;
            f32x4 v = {0.f, 0.f, 0.f, 0.f};
            if (havepf && tid < 32 && xrow < H_)
                v = *(const f32x4*)(xtc + (size_t)xrow * XROWB + off);
            pf8 = v;
        }

        // ---- compute tile t ----
        int slotoff[4];
#pragma unroll
        for (int k = 0; k < 4; ++k) slotoff[k] = ((h0 + k) & 3) * XROWB;

        f32x4 acc[2][7];
#pragma unroll
        for (int m = 0; m < 2; ++m)
#pragma unroll
            for (int nf = 0; nf < 7; ++nf)
                acc[m][nf] = (f32x4){0.f, 0.f, 0.f, 0.f};

#pragma unroll
        for (int dh = 0; dh < 3; ++dh) {
            const char* rowb = xs + slotoff[nw + dh];
#pragma unroll
            for (int dw = 0; dw < 3; ++dw) {
                const unsigned short* wsft = wqa + (dh * 3 + dw) * (C_ * C_);
                const char* colb = rowb + (lcol + dw) * CHUNK;
#pragma unroll
                for (int c0 = 0; c0 < 2; ++c0) {
                    const bf16x8 a0 = *(const bf16x8*)(wsft + c0 * 32);
                    const bf16x8 a1 =
                        *(const bf16x8*)(wsft + 16 * C_ + c0 * 32);
                    const char* cb = colb + koff[dw][c0];
#pragma unroll
                    for (int nf = 0; nf < 7; ++nf) {
                        const bf16x8 bv = *(const bf16x8*)(cb + nf * 2048);
                        acc[0][nf] = __builtin_amdgcn_mfma_f32_16x16x32_bf16(
                            a0, bv, acc[0][nf], 0, 0, 0);
                        acc[1][nf] = __builtin_amdgcn_mfma_f32_16x16x32_bf16(
                            a1, bv, acc[1][nf], 0, 0, 0);
                    }
                }
            }
        }

        // ---- epilogue stores (fire-and-forget; drain at next barrier) ----
        {
            const int h = h0 + nw;
#pragma unroll
            for (int m = 0; m < 2; ++m) {
                const int cobase = mw * 32 + m * 16 + kg * 4;
#pragma unroll
                for (int nf = 0; nf < 7; ++nf) {
                    const int col = nf * 16 + lcol;
#pragma unroll
                    for (int rr = 0; rr < 4; ++rr)
                        out[((size_t)(b * C_ + cobase + rr)) * HW + h * W_ +
                            col] = sc * (acc[m][nf][rr] + bs[m][rr]);
                }
            }
        }

        if (havepf) {
            __syncthreads();   // all waves done reading retiring slots
#pragma unroll
            for (int i = 0; i < 7; ++i) {
                const int q   = tid + 256 * i;
                const int row = (q >= XROWCH) ? 1 : 0;
                const int off = (q - row * XROWCH) * 16;
                const int slot = (h0 + 4 + row) & 3;
                *(f32x4*)(xs + slot * XROWB + off) = pf[i];
            }
            if (tid < 32) {
                const int off = (1792 + tid - XROWCH) * 16;
                *(f32x4*)(xs + ((h0 + 5) & 3) * XROWB + off) = pf8;
            }
            __syncthreads();   // prefetch visible to all
        }
    }
}

extern "C" void kernel_launch(void* const* d_in, const int* in_sizes, int n_in,
                              void* d_out, int out_size, void* d_ws,
                              size_t ws_size, hipStream_t stream) {
    const float* x     = (const float*)d_in[0];
    const float* w     = (const float*)d_in[1];
    const float* bias  = (const float*)d_in[2];
    const float* scale = (const float*)d_in[3];
    float* out         = (float*)d_out;

    unsigned short* wq = (unsigned short*)d_ws;   // 73728 B
    unsigned short* xt = (unsigned short*)((char*)d_ws + WQ_OFF);

    quant_w<<<(C_ * C_ * 9 + 255) / 256, 256, 0, stream>>>(w, wq);
    xform<<<B_ * H_, 256, 0, stream>>>(x, xt);
    conv_mfma<<<NBLKC, 256, 0, stream>>>(xt, wq, bias, scale, out);
}